// Round 1
// baseline (1478.302 us; speedup 1.0000x reference)
//
#include <hip/hip_runtime.h>
#include <hip/hip_fp16.h>

// entmax-1.5 attention, fp32. B=2,H=8 (16 heads), S=2048, D=128.
// Block = 256 threads = 4 waves; 8 query rows per block.
//   wave wid: pr = wid>>1 -> rows [rbase..rbase+3]; kh = wid&1 -> k-half.
// Phase 1: QK^T via d-column-chunk LDS staging; scores live in regs sc[4][16]
//          (k = (kh*16+t)*64 + lane).
// Phase 2: row max + 25-iter bisection for entmax threshold tau (cross-wave
//          partials combined through small LDS buffer).
// Phase 3: p=(z-tau)^2 -> fp16 LDS; PV with V tiles staged 32 k-rows at a time.

constexpr int S = 2048;
constexpr int Dh = 128;

__global__ __launch_bounds__(256, 2)
void entmax_attn_kernel(const float* __restrict__ Q, const float* __restrict__ K,
                        const float* __restrict__ V, float* __restrict__ Out) {
  __shared__ float4 kvbuf[2048];        // 32KB: K col-chunk (ph1) / V tiles (ph3)
  __shared__ __half pbuf[S * 8];        // 32KB: p[k][row 0..7]
  __shared__ float red[4][4];           // per-wave partials (max / f)
  __shared__ float4 outbuf[8 * 32];     // 4KB: cross-wave PV partials

  const int tid  = threadIdx.x;
  const int lane = tid & 63;
  const int wid  = tid >> 6;
  const int pr   = wid >> 1;   // row-group of this wave
  const int kh   = wid & 1;    // k-half of this wave
  const int bh   = blockIdx.y;
  const int rbase = blockIdx.x * 8 + pr * 4;
  const int tbase = kh * 16;

  const size_t hbase = (size_t)bh * S * Dh;
  const float4* Q4 = reinterpret_cast<const float4*>(Q + hbase);
  const float4* K4 = reinterpret_cast<const float4*>(K + hbase);
  const float4* V4 = reinterpret_cast<const float4*>(V + hbase);
  float4* O4 = reinterpret_cast<float4*>(Out + hbase);

  float sc[4][16];
#pragma unroll
  for (int r = 0; r < 4; ++r)
#pragma unroll
    for (int t = 0; t < 16; ++t) sc[r][t] = 0.f;

  // ---------------- Phase 1: scores = Q K^T ----------------
  for (int c = 0; c < 32; ++c) {
    __syncthreads();
#pragma unroll
    for (int i = 0; i < 8; ++i) {
      int idx = i * 256 + tid;                 // k index 0..2047
      kvbuf[idx] = K4[(size_t)idx * 32 + c];   // K[k][4c..4c+3]
    }
    __syncthreads();
    float4 qv[4];
#pragma unroll
    for (int r = 0; r < 4; ++r) qv[r] = Q4[(size_t)(rbase + r) * 32 + c];
#pragma unroll
    for (int t = 0; t < 16; ++t) {
      float4 kv = kvbuf[(tbase + t) * 64 + lane];
#pragma unroll
      for (int r = 0; r < 4; ++r) {
        sc[r][t] = fmaf(qv[r].x, kv.x, sc[r][t]);
        sc[r][t] = fmaf(qv[r].y, kv.y, sc[r][t]);
        sc[r][t] = fmaf(qv[r].z, kv.z, sc[r][t]);
        sc[r][t] = fmaf(qv[r].w, kv.w, sc[r][t]);
      }
    }
  }

  // ---------------- Phase 2: row max + bisection ----------------
  const float scale = 0.08838834764831845f;  // 1/sqrt(128)
  float m[4], tau[4];
#pragma unroll
  for (int r = 0; r < 4; ++r) {
    float mm = -1e30f;
#pragma unroll
    for (int t = 0; t < 16; ++t) { sc[r][t] *= scale; mm = fmaxf(mm, sc[r][t]); }
#pragma unroll
    for (int off = 32; off >= 1; off >>= 1) mm = fmaxf(mm, __shfl_xor(mm, off));
    if (lane == 0) red[wid][r] = mm;
  }
  __syncthreads();
#pragma unroll
  for (int r = 0; r < 4; ++r)
    m[r] = fmaxf(red[pr * 2][r], red[pr * 2 + 1][r]);
  __syncthreads();

  // z = (s - m) * 0.5, z_max = 0, root tau* in [-1, 0]
#pragma unroll
  for (int r = 0; r < 4; ++r)
#pragma unroll
    for (int t = 0; t < 16; ++t) sc[r][t] = (sc[r][t] - m[r]) * 0.5f;

  float lo[4], hi[4];
#pragma unroll
  for (int r = 0; r < 4; ++r) { lo[r] = -1.f; hi[r] = 0.f; }

  for (int it = 0; it < 25; ++it) {
#pragma unroll
    for (int r = 0; r < 4; ++r) {
      float mid = 0.5f * (lo[r] + hi[r]);
      float ff = 0.f;
#pragma unroll
      for (int t = 0; t < 16; ++t) {
        float d = fmaxf(sc[r][t] - mid, 0.f);
        ff = fmaf(d, d, ff);
      }
#pragma unroll
      for (int off = 32; off >= 1; off >>= 1) ff += __shfl_xor(ff, off);
      if (lane == 0) red[wid][r] = ff;
    }
    __syncthreads();
#pragma unroll
    for (int r = 0; r < 4; ++r) {
      float ft = red[pr * 2][r] + red[pr * 2 + 1][r];
      float mid = 0.5f * (lo[r] + hi[r]);
      bool up = (ft >= 1.f);
      lo[r] = up ? mid : lo[r];
      hi[r] = up ? hi[r] : mid;
    }
    __syncthreads();
  }
#pragma unroll
  for (int r = 0; r < 4; ++r) tau[r] = 0.5f * (lo[r] + hi[r]);

  // ---------------- p -> fp16 LDS ----------------
#pragma unroll
  for (int t = 0; t < 16; ++t) {
    int k = (tbase + t) * 64 + lane;
#pragma unroll
    for (int r = 0; r < 4; ++r) {
      float d = fmaxf(sc[r][t] - tau[r], 0.f);
      pbuf[k * 8 + pr * 4 + r] = __float2half(d * d);
    }
  }

  // ---------------- Phase 3: Out = P V ----------------
  float4 acc[4];
#pragma unroll
  for (int r = 0; r < 4; ++r) acc[r] = make_float4(0.f, 0.f, 0.f, 0.f);

  const int ch = lane & 31;   // d-chunk (4 dims)
  const int jh = lane >> 5;   // j-half within 32-row chunk

  for (int mblk = 0; mblk < 32; ++mblk) {
    __syncthreads();
    // stage 32 k-rows of V for each k-half: kvbuf[kh*1024 + jloc*32 + chunk]
#pragma unroll
    for (int i = 0; i < 8; ++i) {
      int idx = i * 256 + tid;            // 0..2047
      int half = idx >> 10;               // which k-half
      int loc = idx & 1023;               // 32 rows x 32 chunks
      int kk = half * 1024 + mblk * 32 + (loc >> 5);
      kvbuf[idx] = V4[(size_t)kk * 32 + (loc & 31)];
    }
    __syncthreads();
#pragma unroll
    for (int jj = 0; jj < 16; ++jj) {
      int j = jh * 16 + jj;
      int k = kh * 1024 + mblk * 32 + j;
      float4 v = kvbuf[kh * 1024 + j * 32 + ch];
      const __half2* ph = reinterpret_cast<const __half2*>(&pbuf[(size_t)k * 8 + pr * 4]);
      float2 p01 = __half22float2(ph[0]);
      float2 p23 = __half22float2(ph[1]);
      acc[0].x = fmaf(p01.x, v.x, acc[0].x);
      acc[0].y = fmaf(p01.x, v.y, acc[0].y);
      acc[0].z = fmaf(p01.x, v.z, acc[0].z);
      acc[0].w = fmaf(p01.x, v.w, acc[0].w);
      acc[1].x = fmaf(p01.y, v.x, acc[1].x);
      acc[1].y = fmaf(p01.y, v.y, acc[1].y);
      acc[1].z = fmaf(p01.y, v.z, acc[1].z);
      acc[1].w = fmaf(p01.y, v.w, acc[1].w);
      acc[2].x = fmaf(p23.x, v.x, acc[2].x);
      acc[2].y = fmaf(p23.x, v.y, acc[2].y);
      acc[2].z = fmaf(p23.x, v.z, acc[2].z);
      acc[2].w = fmaf(p23.x, v.w, acc[2].w);
      acc[3].x = fmaf(p23.y, v.x, acc[3].x);
      acc[3].y = fmaf(p23.y, v.y, acc[3].y);
      acc[3].z = fmaf(p23.y, v.z, acc[3].z);
      acc[3].w = fmaf(p23.y, v.w, acc[3].w);
    }
  }

  // merge j-halves within wave
#pragma unroll
  for (int r = 0; r < 4; ++r) {
    acc[r].x += __shfl_xor(acc[r].x, 32);
    acc[r].y += __shfl_xor(acc[r].y, 32);
    acc[r].z += __shfl_xor(acc[r].z, 32);
    acc[r].w += __shfl_xor(acc[r].w, 32);
  }

  // combine k-halves across wave pair via LDS, kh=0 wave stores to global
  __syncthreads();
  if (kh == 1 && lane < 32) {
#pragma unroll
    for (int r = 0; r < 4; ++r) outbuf[(pr * 4 + r) * 32 + ch] = acc[r];
  }
  __syncthreads();
  if (kh == 0 && lane < 32) {
#pragma unroll
    for (int r = 0; r < 4; ++r) {
      float4 o = outbuf[(pr * 4 + r) * 32 + ch];
      float4 a = acc[r];
      a.x += o.x; a.y += o.y; a.z += o.z; a.w += o.w;
      O4[(size_t)(rbase + r) * 32 + ch] = a;
    }
  }
}

extern "C" void kernel_launch(void* const* d_in, const int* in_sizes, int n_in,
                              void* d_out, int out_size, void* d_ws, size_t ws_size,
                              hipStream_t stream) {
  const float* q = (const float*)d_in[0];
  const float* k = (const float*)d_in[1];
  const float* v = (const float*)d_in[2];
  float* out = (float*)d_out;
  int nheads = in_sizes[0] / (S * Dh);   // B*H = 16
  dim3 grid(S / 8, nheads, 1);
  dim3 block(256, 1, 1);
  entmax_attn_kernel<<<grid, block, 0, stream>>>(q, k, v, out);
}

// Round 3
// 255.768 us; speedup vs baseline: 5.7798x; 5.7798x over previous
//
#include <hip/hip_runtime.h>

// entmax-1.5 attention via f16 MFMA. B*H=16 heads, S=2048, D=128, fp32 I/O.
// Block = 512 threads (8 waves), 32 q-rows. Grid = 1024.
//
// Phase A: swapped QK^T (A=K, B=Q^T) with mfma_f32_32x32x16_f16.
//   Wave w owns k-slice [w*256, w*256+256): 8 k-tiles of 32, acc = 8 x f32x16.
//   C layout: col = lane&31 = q (lane-local row!), row = (r&3)+8*(r>>2)+4*(lane>>5).
// Phase B: row max + 8 Newton iters for entmax tau: f(t)=sum (z-t)+^2 = 1,
//   f' = -2g, tau += (f-1)/(2g). Lane-local partials + shfl_xor(32) + 8-wave LDS.
// Phase C/D: p=(z-tau)^2 -> f16 -> LDS chunk (32q x 256k, XOR-swizzled rows);
//   producer wave c+1 fills buf[(c+1)&1] while all waves PV-consume chunk c with
//   mfma_f32_16x16x32_f16 (wave = 16-d tile, V loaded scalar from L2, cvt to f16).

constexpr int S = 2048;
constexpr int D = 128;

typedef _Float16 f16x8 __attribute__((ext_vector_type(8)));
typedef __fp16  fp16x2 __attribute__((ext_vector_type(2)));
typedef float f32x4 __attribute__((ext_vector_type(4)));
typedef float f32x16 __attribute__((ext_vector_type(16)));

union H8 { f16x8 v; fp16x2 h[4]; };

__device__ __forceinline__ f16x8 cvt8(float4 a, float4 b) {
  H8 r;
  r.h[0] = __builtin_amdgcn_cvt_pkrtz(a.x, a.y);
  r.h[1] = __builtin_amdgcn_cvt_pkrtz(a.z, a.w);
  r.h[2] = __builtin_amdgcn_cvt_pkrtz(b.x, b.y);
  r.h[3] = __builtin_amdgcn_cvt_pkrtz(b.z, b.w);
  return r.v;
}

__global__ __launch_bounds__(512, 2)
void entmax_attn_mfma(const float* __restrict__ Q, const float* __restrict__ K,
                      const float* __restrict__ V, float* __restrict__ O) {
  __shared__ char pbuf[32768];          // 2 x (32 q x 256 k) f16 P chunks
  __shared__ float redmax[8][32];
  __shared__ float2 redfg[2][8][32];

  const int tid  = threadIdx.x;
  const int lane = tid & 63;
  const int wid  = tid >> 6;
  const int l31  = lane & 31;
  const int h    = lane >> 5;
  const int q16  = lane & 15;
  const int g4   = lane >> 4;

  // XCD-aware mapping: 2 heads per XCD -> K/V (4MB) resident in per-XCD L2.
  const int bi   = blockIdx.x;
  const int head = (bi & 7) * 2 + ((bi >> 3) >> 6);
  const int qb   = ((bi >> 3) & 63) * 32;

  const size_t hb = (size_t)head * S * D;
  const float* Qh = Q + hb;
  const float* Kh = K + hb;
  const float* Vh = V + hb;
  float* Oh = O + hb;

  // ---- Q fragments (persistent): B[d][q], q = l31, d = ds*16 + 8h + i ----
  f16x8 qf[8];
  {
    const float* qr = Qh + (size_t)(qb + l31) * D + 8 * h;
#pragma unroll
    for (int ds = 0; ds < 8; ++ds) {
      float4 a = *(const float4*)(qr + ds * 16);
      float4 b = *(const float4*)(qr + ds * 16 + 4);
      qf[ds] = cvt8(a, b);
    }
  }

  // ---- Phase A: scores for wave's 256-k slice ----
  f32x16 acc[8];
#pragma unroll
  for (int t = 0; t < 8; ++t)
#pragma unroll
    for (int e = 0; e < 16; ++e) acc[t][e] = 0.f;

  {
    const float* kr = Kh + (size_t)(wid * 256 + l31) * D + 8 * h;
#pragma unroll
    for (int t = 0; t < 8; ++t) {
#pragma unroll
      for (int ds = 0; ds < 8; ++ds) {
        const float* kp = kr + t * (32 * D) + ds * 16;
        float4 a = *(const float4*)kp;
        float4 b = *(const float4*)(kp + 4);
        f16x8 kf = cvt8(a, b);
        acc[t] = __builtin_amdgcn_mfma_f32_32x32x16_f16(kf, qf[ds], acc[t], 0, 0, 0);
      }
    }
  }

  // ---- Phase B: row max, z-transform, Newton for tau ----
  const float hs = 0.04419417382415922f;  // 0.5 / sqrt(128)
  float mx = -3.4e38f;
#pragma unroll
  for (int t = 0; t < 8; ++t)
#pragma unroll
    for (int e = 0; e < 16; ++e) mx = fmaxf(mx, acc[t][e]);
  mx = fmaxf(mx, __shfl_xor(mx, 32));
  if (lane < 32) redmax[wid][l31] = mx;
  __syncthreads();
  float m = redmax[0][l31];
#pragma unroll
  for (int w = 1; w < 8; ++w) m = fmaxf(m, redmax[w][l31]);

  const float bz = -m * hs;   // z = raw*hs - max*hs, zmax = 0
#pragma unroll
  for (int t = 0; t < 8; ++t)
#pragma unroll
    for (int e = 0; e < 16; ++e) acc[t][e] = fmaf(acc[t][e], hs, bz);

  float tau = -1.f;
  for (int it = 0; it < 8; ++it) {
    float f = 0.f, g = 0.f;
#pragma unroll
    for (int t = 0; t < 8; ++t)
#pragma unroll
      for (int e = 0; e < 16; ++e) {
        float d = fmaxf(acc[t][e] - tau, 0.f);
        f = fmaf(d, d, f);
        g += d;
      }
    f += __shfl_xor(f, 32);
    g += __shfl_xor(g, 32);
    if (lane < 32) redfg[it & 1][wid][l31] = make_float2(f, g);
    __syncthreads();
    f = 0.f; g = 0.f;
#pragma unroll
    for (int w = 0; w < 8; ++w) {
      float2 r = redfg[it & 1][w][l31];
      f += r.x; g += r.y;
    }
    tau += (f - 1.f) / (2.f * fmaxf(g, 1e-20f));
  }

  // ---- write this wave's P chunk (32q x 256k f16, XOR-swizzled rows) ----
  auto writeP = [&](int buf) {
    char* pb = pbuf + buf * 16384;
    const int sw = (l31 & 7) << 4;
#pragma unroll
    for (int t = 0; t < 8; ++t) {
#pragma unroll
      for (int rp = 0; rp < 8; ++rp) {
        const int r0 = rp * 2;
        float d0 = fmaxf(acc[t][r0] - tau, 0.f);
        float d1 = fmaxf(acc[t][r0 + 1] - tau, 0.f);
        fp16x2 p = __builtin_amdgcn_cvt_pkrtz(d0 * d0, d1 * d1);
        const int k = t * 32 + 8 * (r0 >> 2) + 4 * h + (r0 & 3);
        const int off = (l31 * 512 + k * 2) ^ sw;
        *(fp16x2*)(pb + off) = p;
      }
    }
  };

  // ---- Phase D: Out = P V, streamed over 8 chunks ----
  f32x4 oa0 = {0.f, 0.f, 0.f, 0.f};
  f32x4 oa1 = {0.f, 0.f, 0.f, 0.f};
  const float* vcol = Vh + (size_t)(8 * g4) * D + wid * 16 + q16;
  const int sw = (q16 & 7) << 4;

  if (wid == 0) writeP(0);
  __syncthreads();

  for (int c = 0; c < 8; ++c) {
    if (wid == c + 1) writeP((c + 1) & 1);
    const char* pb = pbuf + (c & 1) * 16384;
    for (int ks = 0; ks < 8; ++ks) {
      const float* vp = vcol + (size_t)(c * 256 + ks * 32) * D;
      float v0 = vp[0 * D], v1 = vp[1 * D], v2 = vp[2 * D], v3 = vp[3 * D];
      float v4 = vp[4 * D], v5 = vp[5 * D], v6 = vp[6 * D], v7 = vp[7 * D];
      H8 bf;
      bf.h[0] = __builtin_amdgcn_cvt_pkrtz(v0, v1);
      bf.h[1] = __builtin_amdgcn_cvt_pkrtz(v2, v3);
      bf.h[2] = __builtin_amdgcn_cvt_pkrtz(v4, v5);
      bf.h[3] = __builtin_amdgcn_cvt_pkrtz(v6, v7);
      const int ob = ks * 64 + g4 * 16;
      f16x8 A0 = *(const f16x8*)(pb + ((q16 * 512 + ob) ^ sw));
      f16x8 A1 = *(const f16x8*)(pb + (((q16 + 16) * 512 + ob) ^ sw));
      oa0 = __builtin_amdgcn_mfma_f32_16x16x32_f16(A0, bf.v, oa0, 0, 0, 0);
      oa1 = __builtin_amdgcn_mfma_f32_16x16x32_f16(A1, bf.v, oa1, 0, 0, 0);
    }
    __syncthreads();
  }

  // ---- store: C layout col = q16 = d-in-tile, row = 4*g4 + r ----
  float* op = Oh + (size_t)(qb + 4 * g4) * D + wid * 16 + q16;
#pragma unroll
  for (int r = 0; r < 4; ++r) {
    op[(size_t)r * D]        = oa0[r];
    op[(size_t)(16 + r) * D] = oa1[r];
  }
}

extern "C" void kernel_launch(void* const* d_in, const int* in_sizes, int n_in,
                              void* d_out, int out_size, void* d_ws, size_t ws_size,
                              hipStream_t stream) {
  const float* q = (const float*)d_in[0];
  const float* k = (const float*)d_in[1];
  const float* v = (const float*)d_in[2];
  float* out = (float*)d_out;
  dim3 grid(1024, 1, 1);   // 16 heads x 64 q-chunks, XCD-swizzled in-kernel
  dim3 block(512, 1, 1);
  entmax_attn_mfma<<<grid, block, 0, stream>>>(q, k, v, out);
}

// Round 4
// 160.091 us; speedup vs baseline: 9.2342x; 1.5976x over previous
//
#include <hip/hip_runtime.h>

// entmax-1.5 attention via f16 MFMA, round 4.
// B*H=16 heads, S=2048, D=128, fp32 I/O. Block = 512 threads (8 waves), 32 q.
//
// Phase A: swapped QK^T (A=K, B=Q) with mfma_f32_32x32x16_f16.
//   K staged per-wave via global_load_lds (pre-swizzled source, swizzled read,
//   rule-21 both-sides XOR (row&7)<<4). No barriers: each wave stages/reads
//   only its own 32-row region; vmcnt(0)/lgkmcnt(0) fences per tile.
// Phase B: row max (f32 acc) -> z packed to f16 pairs (v2h z16[64]) ->
//   8 Newton iters on packed data: v_pk_sub/max + v_dot2_f32_f16.
// Phase C/D: p=(z-tau)^2 in packed f16 -> pbuf (aliases kbuf); producer wave
//   c+1 fills buf[(c+1)&1] while all waves consume chunk c with
//   mfma_f32_16x16x32_f16. V from f16 prepass buffer (or f32 fallback).
//
// Host: prepass converts K,V -> f16 in d_ws if ws_size allows; else f32 path.

constexpr int S = 2048;
constexpr int D = 128;
constexpr int NH = 16;

typedef _Float16 f16x8 __attribute__((ext_vector_type(8)));
typedef _Float16 f16x4 __attribute__((ext_vector_type(4)));
typedef _Float16 v2h   __attribute__((ext_vector_type(2)));
typedef __fp16   fp16x2 __attribute__((ext_vector_type(2)));
typedef float f32x4  __attribute__((ext_vector_type(4)));
typedef float f32x16 __attribute__((ext_vector_type(16)));

union H8 { f16x8 v; fp16x2 h[4]; };
union PK { fp16x2 a; v2h b; };

__device__ __forceinline__ f16x8 cvt8(float4 a, float4 b) {
  H8 r;
  r.h[0] = __builtin_amdgcn_cvt_pkrtz(a.x, a.y);
  r.h[1] = __builtin_amdgcn_cvt_pkrtz(a.z, a.w);
  r.h[2] = __builtin_amdgcn_cvt_pkrtz(b.x, b.y);
  r.h[3] = __builtin_amdgcn_cvt_pkrtz(b.z, b.w);
  return r.v;
}

#define GLL16(gp, lp) __builtin_amdgcn_global_load_lds(                      \
    (const __attribute__((address_space(1))) void*)(gp),                    \
    (__attribute__((address_space(3))) void*)(lp), 16, 0, 0)

__global__ void prepass_f16(const float* __restrict__ K, const float* __restrict__ V,
                            _Float16* __restrict__ K16, _Float16* __restrict__ V16) {
  int i = blockIdx.x * 256 + threadIdx.x;   // grid sized exactly: NH*S*D/4
  float4 k4 = reinterpret_cast<const float4*>(K)[i];
  float4 v4 = reinterpret_cast<const float4*>(V)[i];
  f16x4 ko = {(_Float16)k4.x, (_Float16)k4.y, (_Float16)k4.z, (_Float16)k4.w};
  f16x4 vo = {(_Float16)v4.x, (_Float16)v4.y, (_Float16)v4.z, (_Float16)v4.w};
  reinterpret_cast<f16x4*>(K16)[i] = ko;
  reinterpret_cast<f16x4*>(V16)[i] = vo;
}

template<bool F16>
__global__ __launch_bounds__(512, 2)
void entmax_attn(const float* __restrict__ Q, const float* __restrict__ K,
                 const float* __restrict__ V, const _Float16* __restrict__ K16,
                 const _Float16* __restrict__ V16, float* __restrict__ O) {
  constexpr int ROWB = F16 ? 256 : 512;       // bytes per staged K row
  constexpr int KBUF = 256 * ROWB;            // 64KB (f16) / 128KB (f32)
  __shared__ __align__(16) char smem[KBUF];   // kbuf (phase A) U pbuf (phase D)
  __shared__ float  redmax[8][32];
  __shared__ float2 redfg[2][8][32];

  const int tid  = threadIdx.x;
  const int lane = tid & 63;
  const int wid  = tid >> 6;
  const int l31  = lane & 31;
  const int h    = lane >> 5;
  const int q16  = lane & 15;
  const int g4   = lane >> 4;

  // XCD-aware mapping: 2 heads per XCD -> K/V resident in per-XCD L2.
  const int bi   = blockIdx.x;
  const int head = (bi & 7) * 2 + ((bi >> 3) >> 6);
  const int qb   = ((bi >> 3) & 63) * 32;

  const size_t hb = (size_t)head * S * D;
  const float* Qh = Q + hb;
  const float* Kh = K + hb;
  const float* Vh = V + hb;
  const _Float16* K16h = K16 + hb;
  const _Float16* V16h = V16 + hb;
  float* Oh = O + hb;

  char* kreg = smem + wid * 32 * ROWB;        // this wave's private stage region

  // ---- stage K tile t (32 rows of this wave's k-slice) via global_load_lds ----
  auto stage = [&](int t) {
    if constexpr (F16) {
#pragma unroll
      for (int i = 0; i < 8; ++i) {           // 8 x 1KB, 4 rows each
        const int rr = 4 * i + (lane >> 4);   // local row 0..31
        const size_t grow = (size_t)(wid * 256 + t * 32 + rr);
        const char* gp = (const char*)K16h + grow * 256 +
                         (((lane & 15) * 16) ^ ((rr & 7) << 4));
        GLL16(gp, kreg + i * 1024);
      }
    } else {
#pragma unroll
      for (int i = 0; i < 16; ++i) {          // 16 x 1KB, 2 rows each
        const int rr = 2 * i + (lane >> 5);
        const size_t grow = (size_t)(wid * 256 + t * 32 + rr);
        const char* gp = (const char*)Kh + grow * 512 +
                         (((lane & 31) * 16) ^ ((rr & 7) << 4));
        GLL16(gp, kreg + i * 1024);
      }
    }
  };

  stage(0);

  // ---- Q fragments (persistent): B[d][q], q = l31, d = ds*16 + 8h + i ----
  f16x8 qf[8];
  {
    const float* qr = Qh + (size_t)(qb + l31) * D + 8 * h;
#pragma unroll
    for (int ds = 0; ds < 8; ++ds) {
      float4 a = *(const float4*)(qr + ds * 16);
      float4 b = *(const float4*)(qr + ds * 16 + 4);
      qf[ds] = cvt8(a, b);
    }
  }

  // ---- Phase A: scores for wave's 256-k slice (barrier-free) ----
  f32x16 acc[8];
#pragma unroll
  for (int t = 0; t < 8; ++t)
#pragma unroll
    for (int e = 0; e < 16; ++e) acc[t][e] = 0.f;

  const int swk = (l31 & 7) << 4;
#pragma unroll
  for (int t = 0; t < 8; ++t) {
    asm volatile("s_waitcnt vmcnt(0)" ::: "memory");
    __builtin_amdgcn_sched_barrier(0);
    if constexpr (F16) {
#pragma unroll
      for (int ds = 0; ds < 8; ++ds) {
        f16x8 kf = *(const f16x8*)(kreg + l31 * 256 + ((ds * 32 + 16 * h) ^ swk));
        acc[t] = __builtin_amdgcn_mfma_f32_32x32x16_f16(kf, qf[ds], acc[t], 0, 0, 0);
      }
    } else {
#pragma unroll
      for (int ds = 0; ds < 8; ++ds) {
        const int y = ds * 64 + 32 * h;
        float4 a = *(const float4*)(kreg + l31 * 512 + (y ^ swk));
        float4 b = *(const float4*)(kreg + l31 * 512 + ((y + 16) ^ swk));
        f16x8 kf = cvt8(a, b);
        acc[t] = __builtin_amdgcn_mfma_f32_32x32x16_f16(kf, qf[ds], acc[t], 0, 0, 0);
      }
    }
    asm volatile("s_waitcnt lgkmcnt(0)" ::: "memory");
    __builtin_amdgcn_sched_barrier(0);
    if (t < 7) stage(t + 1);
  }

  // ---- Phase B: row max -> packed f16 z -> Newton for tau ----
  const float hs = 0.04419417382415922f;  // 0.5 / sqrt(128)
  float mx = -3.4e38f;
#pragma unroll
  for (int t = 0; t < 8; ++t)
#pragma unroll
    for (int e = 0; e < 16; ++e) mx = fmaxf(mx, acc[t][e]);
  mx = fmaxf(mx, __shfl_xor(mx, 32));
  if (lane < 32) redmax[wid][l31] = mx;
  __syncthreads();
  float m = redmax[0][l31];
#pragma unroll
  for (int w = 1; w < 8; ++w) m = fmaxf(m, redmax[w][l31]);

  const float bz = -m * hs;
  v2h z16[64];
#pragma unroll
  for (int t = 0; t < 8; ++t)
#pragma unroll
    for (int j = 0; j < 8; ++j) {
      float a0 = fmaf(acc[t][2 * j], hs, bz);
      float a1 = fmaf(acc[t][2 * j + 1], hs, bz);
      PK pk; pk.a = __builtin_amdgcn_cvt_pkrtz(a0, a1);
      z16[t * 8 + j] = pk.b;
    }

  const v2h zero2 = {(_Float16)0.f, (_Float16)0.f};
  const v2h one2  = {(_Float16)1.f, (_Float16)1.f};
  float tau = -1.f;
  for (int it = 0; it < 8; ++it) {
    const _Float16 th = (_Float16)tau;
    const v2h tt = {th, th};
    float f = 0.f, g = 0.f;
#pragma unroll
    for (int j = 0; j < 64; ++j) {
      v2h d = __builtin_elementwise_max(z16[j] - tt, zero2);
#if __has_builtin(__builtin_amdgcn_fdot2)
      f = __builtin_amdgcn_fdot2(d, d, f, false);
      g = __builtin_amdgcn_fdot2(d, one2, g, false);
#else
      float d0 = (float)d[0], d1 = (float)d[1];
      f = fmaf(d0, d0, fmaf(d1, d1, f));
      g += d0 + d1;
#endif
    }
    f += __shfl_xor(f, 32);
    g += __shfl_xor(g, 32);
    if (lane < 32) redfg[it & 1][wid][l31] = make_float2(f, g);
    __syncthreads();
    f = 0.f; g = 0.f;
#pragma unroll
    for (int w = 0; w < 8; ++w) {
      float2 r = redfg[it & 1][w][l31];
      f += r.x; g += r.y;
    }
    tau += (f - 1.f) / (2.f * fmaxf(g, 1e-20f));
  }

  // ---- write this wave's P chunk (32q x 256k f16, XOR-swizzled rows) ----
  auto writeP = [&](int buf) {
    char* pb = smem + buf * 16384;
    const int sw = (l31 & 7) << 4;
    const _Float16 th = (_Float16)tau;
    const v2h tt = {th, th};
#pragma unroll
    for (int t = 0; t < 8; ++t) {
#pragma unroll
      for (int j = 0; j < 8; ++j) {
        v2h d = __builtin_elementwise_max(z16[t * 8 + j] - tt, zero2);
        v2h p = d * d;
        const int r0 = 2 * j;
        const int k = t * 32 + 8 * (r0 >> 2) + 4 * h + (r0 & 3);
        const int off = (l31 * 512 + k * 2) ^ sw;
        *(v2h*)(pb + off) = p;
      }
    }
  };

  // ---- Phase D: Out = P V, streamed over 8 chunks ----
  f32x4 oa0 = {0.f, 0.f, 0.f, 0.f};
  f32x4 oa1 = {0.f, 0.f, 0.f, 0.f};
  const int sw = (q16 & 7) << 4;

  if (wid == 0) writeP(0);
  __syncthreads();

  for (int c = 0; c < 8; ++c) {
    if (wid == c + 1) writeP((c + 1) & 1);
    const char* pb = smem + (c & 1) * 16384;
#pragma unroll 1
    for (int ks = 0; ks < 8; ++ks) {
      H8 bf;
      if constexpr (F16) {
        const _Float16* vp = V16h + (size_t)(c * 256 + ks * 32 + 8 * g4) * D + wid * 16 + q16;
        f16x8 bv;
        bv[0] = vp[0 * D]; bv[1] = vp[1 * D]; bv[2] = vp[2 * D]; bv[3] = vp[3 * D];
        bv[4] = vp[4 * D]; bv[5] = vp[5 * D]; bv[6] = vp[6 * D]; bv[7] = vp[7 * D];
        bf.v = bv;
      } else {
        const float* vp = Vh + (size_t)(c * 256 + ks * 32 + 8 * g4) * D + wid * 16 + q16;
        float v0 = vp[0 * D], v1 = vp[1 * D], v2 = vp[2 * D], v3 = vp[3 * D];
        float v4 = vp[4 * D], v5 = vp[5 * D], v6 = vp[6 * D], v7 = vp[7 * D];
        bf.h[0] = __builtin_amdgcn_cvt_pkrtz(v0, v1);
        bf.h[1] = __builtin_amdgcn_cvt_pkrtz(v2, v3);
        bf.h[2] = __builtin_amdgcn_cvt_pkrtz(v4, v5);
        bf.h[3] = __builtin_amdgcn_cvt_pkrtz(v6, v7);
      }
      const int ob = ks * 64 + g4 * 16;
      f16x8 A0 = *(const f16x8*)(pb + ((q16 * 512 + ob) ^ sw));
      f16x8 A1 = *(const f16x8*)(pb + (((q16 + 16) * 512 + ob) ^ sw));
      oa0 = __builtin_amdgcn_mfma_f32_16x16x32_f16(A0, bf.v, oa0, 0, 0, 0);
      oa1 = __builtin_amdgcn_mfma_f32_16x16x32_f16(A1, bf.v, oa1, 0, 0, 0);
    }
    __syncthreads();
  }

  // ---- store: C layout col = q16 = d-in-tile, row = 4*g4 + r ----
  float* op = Oh + (size_t)(qb + 4 * g4) * D + wid * 16 + q16;
#pragma unroll
  for (int r = 0; r < 4; ++r) {
    op[(size_t)r * D]        = oa0[r];
    op[(size_t)(16 + r) * D] = oa1[r];
  }
}

extern "C" void kernel_launch(void* const* d_in, const int* in_sizes, int n_in,
                              void* d_out, int out_size, void* d_ws, size_t ws_size,
                              hipStream_t stream) {
  const float* q = (const float*)d_in[0];
  const float* k = (const float*)d_in[1];
  const float* v = (const float*)d_in[2];
  float* out = (float*)d_out;

  const size_t nelem = (size_t)NH * S * D;          // 4.19M per tensor
  const size_t need  = nelem * 2 * sizeof(_Float16); // K16 + V16 = 16.8MB
  dim3 grid(1024, 1, 1), block(512, 1, 1);

  if (ws_size >= need) {
    _Float16* k16 = (_Float16*)d_ws;
    _Float16* v16 = k16 + nelem;
    prepass_f16<<<dim3(nelem / 4 / 256), dim3(256), 0, stream>>>(k, v, k16, v16);
    entmax_attn<true><<<grid, block, 0, stream>>>(q, k, v, k16, v16, out);
  } else {
    entmax_attn<false><<<grid, block, 0, stream>>>(q, k, v, nullptr, nullptr, out);
  }
}